// Round 6
// baseline (705.145 us; speedup 1.0000x reference)
//
#include <hip/hip_runtime.h>

// CRF Viterbi decode (B=512, T=512, S=64).
// R14 = R13 + __launch_bounds__(512, 2): same 8-waves/block TLP design, but
// with the occupancy contract that prevents the spill that invalidated R13.
//
// R13 post-mortem: VGPR_Count=52 for a body needing ~130 (tr[64] + prefetch)
// => hipcc's default occupancy heuristic for multi-wave blocks targeted
// 8 waves/EU (VGPR<=64) and spilled tr[64]+lg/mk arrays to scratch; every
// step re-loaded 64 transitions/lane from scratch (dur 633us, VALUBusy on
// active CUs ~84% of pure spill traffic). R10's identical body in a 64-thread
// block compiled to 132 VGPR, no spill. Fix: __launch_bounds__(512, 2) =
// min 2 waves/EU => VGPR cap 256 => no spill, while 8 waves/block still put
// 2 waves on each SIMD -- the TLP that hides the readlane/cmp-cndmask stalls
// (R9, the best measured config at 284us, was the only prior variant with
// 2 waves/SIMD; R10/R11/R12 all ran one wave per SIMD and stalled).
//
// Backpointers stream to global workspace (coalesced 256B/group/wave,
// fire-and-forget; backtrace reads them back through L2). ys stays in LDS.
// Host falls back to the validated R10 single-wave kernel if ws too small.
//
// Per-wave body is R10's validated code: readlane broadcast, 8 running
// argmax chains of 8 (strict >, ascending p => first-argmax, exact jnp
// semantics), left-priority merge, fmaxf keeps identical values on ties.
// Output: out[0..B) = path_score, out[B + b*(T-1) + t] = (float)tag.

constexpr int Bz = 512;
constexpr int Tz = 512;
constexpr int Sz = 64;
constexpr int WPB = 8;                       // waves (= batches) per block
constexpr float NEGINF = -10000.0f;
constexpr size_t BP_DWORDS_PER_BATCH = 128 * 64;   // packed 4 steps/dword
constexpr size_t WS_NEEDED = (size_t)Bz * BP_DWORDS_PER_BATCH * 4;  // 16 MB

__device__ __forceinline__ float rlf(float x, int lane) {
    return __int_as_float(__builtin_amdgcn_readlane(__float_as_int(x), lane));
}

// -------- R14 wide kernel: 8 waves/block, 2 waves/SIMD, bp in global --------
__global__ __launch_bounds__(WPB * 64, 2)    // min 2 waves/EU -> VGPR cap 256
void crf_viterbi_wide(const float* __restrict__ logits,
                      const float* __restrict__ masks,
                      const float* __restrict__ trans,
                      float* __restrict__ out,
                      unsigned* __restrict__ bpg)
{
    const int n  = threadIdx.x & 63;                                  // lane id == tag id
    const int wv = __builtin_amdgcn_readfirstlane(threadIdx.x >> 6);  // wave id 0..7
    const int b  = blockIdx.x * WPB + wv;                             // this wave's batch

    unsigned* __restrict__ bpw = bpg + (size_t)b * BP_DWORDS_PER_BATCH;

    __shared__ float ys[WPB][512];           // emitted tags per wave, 16 KB

    // full transitions row for this lane's tag: tr[p] = trans[n][p]
    float tr[64];
    {
        const float4* tr4 = reinterpret_cast<const float4*>(trans + (size_t)n * Sz);
        #pragma unroll
        for (int k = 0; k < 16; ++k) {
            float4 t = tr4[k];
            tr[4 * k + 0] = t.x; tr[4 * k + 1] = t.y;
            tr[4 * k + 2] = t.z; tr[4 * k + 3] = t.w;
        }
    }

    float fv = (n == 0) ? 0.0f : NEGINF;

    const float* lgbase = logits + (size_t)b * Tz * Sz;
    const float* mkbase = masks + (size_t)b * Tz;

    // group-of-4 software-pipelined prefetch (2 groups deep)
    float lgc[4], lgn[4], mkc[4], mkn[4];
    #pragma unroll
    for (int k = 0; k < 4; ++k) {
        lgc[k] = lgbase[(1 + k) * Sz + n];
        mkc[k] = mkbase[1 + k];
        lgn[k] = lgbase[(5 + k) * Sz + n];
        mkn[k] = mkbase[5 + k];
    }

    unsigned pk = 0;

    // ---- one Viterbi step (R10's validated body; literal lanes) ----
    auto step = [&](int k, float lg, float mk) -> float {
        float m[8]; int id[8];
        #pragma unroll
        for (int c = 0; c < 8; ++c) {
            m[c]  = rlf(fv, 8 * c) + tr[8 * c];
            id[c] = 8 * c;
            #pragma unroll
            for (int j = 1; j < 8; ++j) {
                const int p = 8 * c + j;
                float cand = rlf(fv, p) + tr[p];
                bool g = cand > m[c];          // uses OLD m[c]
                id[c] = g ? p : id[c];
                m[c]  = fmaxf(m[c], cand);
            }
        }
        #pragma unroll
        for (int st = 1; st < 8; st <<= 1) {
            #pragma unroll
            for (int c = 0; c < 8; c += 2 * st) {
                bool g = m[c + st] > m[c];
                id[c] = g ? id[c + st] : id[c];
                m[c]  = fmaxf(m[c], m[c + st]);
            }
        }
        pk |= ((unsigned)id[0]) << (8 * k);
        float mm = m[0];
        fv = mm + lg * mk;                     // mask multiplies emission only
        return mm;                             // pre-feat max (for path_score)
    };

    // main: groups g = 0..126 cover steps i = 4g+k (i <= 507)
    for (int g = 0; g < 127; ++g) {
        step(0, lgc[0], mkc[0]);
        step(1, lgc[1], mkc[1]);
        step(2, lgc[2], mkc[2]);
        step(3, lgc[3], mkc[3]);

        bpw[g * 64 + n] = pk;                  // coalesced 256B, fire-and-forget
        pk = 0;

        // rotate prefetch; issue loads for group g+2 (rows 4g+9 .. 4g+12)
        #pragma unroll
        for (int k = 0; k < 4; ++k) { lgc[k] = lgn[k]; mkc[k] = mkn[k]; }
        #pragma unroll
        for (int k = 0; k < 4; ++k) {
            int t = 4 * g + 9 + k;
            t = (t < Tz) ? t : (Tz - 1);
            lgn[k] = lgbase[t * Sz + n];
            mkn[k] = mkbase[t];
        }
    }

    // tail: steps 508, 509, 510 (group 127, k = 0..2)
    step(0, lgc[0], mkc[0]);
    step(1, lgc[1], mkc[1]);
    float psc = step(2, lgc[2], mkc[2]);
    bpw[127 * 64 + n] = pk;                    // flush steps 508..510
    if (n == 63) out[b] = psc;                 // path_score = vmaxs[-1][:,63]

    // make our own bp stores visible to our own loads
    asm volatile("s_waitcnt vmcnt(0)" ::: "memory");

    // ---- backtrace (intra-wave; R10's validated readlane chain, bp from global) ----
    unsigned wcur = bpw[127 * 64 + n];
    int w127_63 = __builtin_amdgcn_readlane((int)wcur, 63);
    int tag = (w127_63 >> 16) & 255;           // t0 = bptrs[510][63]

    for (int g = 127; g >= 0; --g) {
        unsigned wnext = (g > 0) ? bpw[(g - 1) * 64 + n] : 0u;  // prefetch (L2)
        const int smax = (g == 127) ? 2 : 3;
        for (int s = smax; s >= 0; --s) {
            int idx = 4 * g + s;
            if (n == 0) ys[wv][idx] = (float)tag;  // emit BEFORE following ptr
            int wd = __builtin_amdgcn_readlane((int)wcur, tag);  // tag is uniform
            tag = (wd >> (8 * s)) & 255;
        }
        wcur = wnext;
    }

    // same-wave LDS ordering: lane-0 writes above complete before these reads
    float* outseq = out + Bz + (size_t)b * (Tz - 1);
    for (int k = n; k < Tz - 1; k += 64) outseq[k] = ys[wv][k];
}

// ---------------- fallback: R10 kernel (validated, 356 us) ----------------
__global__ __launch_bounds__(64)
void crf_viterbi_kernel(const float* __restrict__ logits,
                        const float* __restrict__ masks,
                        const float* __restrict__ trans,
                        float* __restrict__ out)
{
    const int n = threadIdx.x;
    const int b = blockIdx.x;

    __shared__ unsigned bp[128 * 64];
    __shared__ float ys[Tz - 1];

    float tr[64];
    {
        const float4* tr4 = reinterpret_cast<const float4*>(trans + (size_t)n * Sz);
        #pragma unroll
        for (int k = 0; k < 16; ++k) {
            float4 t = tr4[k];
            tr[4 * k + 0] = t.x; tr[4 * k + 1] = t.y;
            tr[4 * k + 2] = t.z; tr[4 * k + 3] = t.w;
        }
    }

    float fv = (n == 0) ? 0.0f : NEGINF;

    const float* lgbase = logits + (size_t)b * Tz * Sz;
    const float* mkbase = masks + (size_t)b * Tz;

    float lgc[4], lgn[4], mkc[4], mkn[4];
    #pragma unroll
    for (int k = 0; k < 4; ++k) {
        lgc[k] = lgbase[(1 + k) * Sz + n];
        mkc[k] = mkbase[1 + k];
        lgn[k] = lgbase[(5 + k) * Sz + n];
        mkn[k] = mkbase[5 + k];
    }

    unsigned pk = 0;

    auto step = [&](int k, float lg, float mk) -> float {
        float m[8]; int id[8];
        #pragma unroll
        for (int c = 0; c < 8; ++c) {
            m[c]  = rlf(fv, 8 * c) + tr[8 * c];
            id[c] = 8 * c;
            #pragma unroll
            for (int j = 1; j < 8; ++j) {
                const int p = 8 * c + j;
                float cand = rlf(fv, p) + tr[p];
                bool g = cand > m[c];
                id[c] = g ? p : id[c];
                m[c]  = fmaxf(m[c], cand);
            }
        }
        #pragma unroll
        for (int st = 1; st < 8; st <<= 1) {
            #pragma unroll
            for (int c = 0; c < 8; c += 2 * st) {
                bool g = m[c + st] > m[c];
                id[c] = g ? id[c + st] : id[c];
                m[c]  = fmaxf(m[c], m[c + st]);
            }
        }
        pk |= ((unsigned)id[0]) << (8 * k);
        float mm = m[0];
        fv = mm + lg * mk;
        return mm;
    };

    for (int g = 0; g < 127; ++g) {
        step(0, lgc[0], mkc[0]);
        step(1, lgc[1], mkc[1]);
        step(2, lgc[2], mkc[2]);
        step(3, lgc[3], mkc[3]);

        bp[g * 64 + n] = pk;
        pk = 0;

        #pragma unroll
        for (int k = 0; k < 4; ++k) { lgc[k] = lgn[k]; mkc[k] = mkn[k]; }
        #pragma unroll
        for (int k = 0; k < 4; ++k) {
            int t = 4 * g + 9 + k;
            t = (t < Tz) ? t : (Tz - 1);
            lgn[k] = lgbase[t * Sz + n];
            mkn[k] = mkbase[t];
        }
    }

    step(0, lgc[0], mkc[0]);
    step(1, lgc[1], mkc[1]);
    float psc = step(2, lgc[2], mkc[2]);
    bp[127 * 64 + n] = pk;
    if (n == 63) out[b] = psc;

    unsigned wcur = bp[127 * 64 + n];
    int w127_63 = __builtin_amdgcn_readlane((int)wcur, 63);
    int tag = (w127_63 >> 16) & 255;

    for (int g = 127; g >= 0; --g) {
        unsigned wnext = (g > 0) ? bp[(g - 1) * 64 + n] : 0u;
        const int smax = (g == 127) ? 2 : 3;
        for (int s = smax; s >= 0; --s) {
            int idx = 4 * g + s;
            if (n == 0) ys[idx] = (float)tag;
            int wd = __builtin_amdgcn_readlane((int)wcur, tag);
            tag = (wd >> (8 * s)) & 255;
        }
        wcur = wnext;
    }

    __syncthreads();
    float* outseq = out + Bz + (size_t)b * (Tz - 1);
    for (int k = n; k < Tz - 1; k += 64) outseq[k] = ys[k];
}

extern "C" void kernel_launch(void* const* d_in, const int* in_sizes, int n_in,
                              void* d_out, int out_size, void* d_ws, size_t ws_size,
                              hipStream_t stream) {
    const float* logits = (const float*)d_in[0];
    const float* masks  = (const float*)d_in[1];
    const float* trans  = (const float*)d_in[2];
    float* out = (float*)d_out;
    (void)in_sizes; (void)n_in; (void)out_size;

    if (d_ws != nullptr && ws_size >= WS_NEEDED) {
        crf_viterbi_wide<<<dim3(Bz / WPB), dim3(WPB * 64), 0, stream>>>(
            logits, masks, trans, out, (unsigned*)d_ws);
    } else {
        crf_viterbi_kernel<<<dim3(Bz), dim3(64), 0, stream>>>(logits, masks, trans, out);
    }
}

// Round 7
// 654.138 us; speedup vs baseline: 1.0780x; 1.0780x over previous
//
#include <hip/hip_runtime.h>

// CRF Viterbi decode (B=512, T=512, S=64).
// R15 = R14 + __attribute__((amdgpu_waves_per_eu(2, 2))).
//
// R13/R14 post-mortem: VGPR_Count=52 both times, identical 633us.
// __launch_bounds__(512,2) only RAISES the VGPR cap (min waves/EU); the
// AMDGPU allocator still targets MAX occupancy and hit 8 waves/EU (<=64
// VGPR) by REMATERIALIZING the tr[64] loads from global inside the loop
// (not scratch: FETCH_SIZE delta was only the planned bp readback; trans is
// a 16KB L1-resident table). So every step re-issued 16 dwordx4 loads whose
// latency sat on the serial chain. The fix is an occupancy CEILING:
// amdgpu_waves_per_eu(2,2) pins the allocator's target at 2 waves/EU
// (VGPR budget 256/wave) so tr[64] + prefetch stay in registers, while the
// 8-wave workgroup still places 2 waves on each SIMD -- the hardware TLP
// that hides readlane/cmp-cndmask stalls (the mechanism behind R9, the best
// measured config; R10/R11/R12 all ran 1 wave/SIMD and stalled).
//
// Backpointers stream to global workspace (coalesced 256B/group/wave,
// fire-and-forget; backtrace reads them back through L2). ys stays in LDS.
// Host falls back to the validated R10 single-wave kernel if ws too small.
//
// Per-wave body is R10's validated code: readlane broadcast, 8 running
// argmax chains of 8 (strict >, ascending p => first-argmax, exact jnp
// semantics), left-priority merge, fmaxf keeps identical values on ties.
// Output: out[0..B) = path_score, out[B + b*(T-1) + t] = (float)tag.

constexpr int Bz = 512;
constexpr int Tz = 512;
constexpr int Sz = 64;
constexpr int WPB = 8;                       // waves (= batches) per block
constexpr float NEGINF = -10000.0f;
constexpr size_t BP_DWORDS_PER_BATCH = 128 * 64;   // packed 4 steps/dword
constexpr size_t WS_NEEDED = (size_t)Bz * BP_DWORDS_PER_BATCH * 4;  // 16 MB

__device__ __forceinline__ float rlf(float x, int lane) {
    return __int_as_float(__builtin_amdgcn_readlane(__float_as_int(x), lane));
}

// -------- R15 wide kernel: 8 waves/block, 2 waves/SIMD, bp in global --------
__global__ __launch_bounds__(WPB * 64)
__attribute__((amdgpu_waves_per_eu(2, 2)))   // pin allocator target: no remat
void crf_viterbi_wide(const float* __restrict__ logits,
                      const float* __restrict__ masks,
                      const float* __restrict__ trans,
                      float* __restrict__ out,
                      unsigned* __restrict__ bpg)
{
    const int n  = threadIdx.x & 63;                                  // lane id == tag id
    const int wv = __builtin_amdgcn_readfirstlane(threadIdx.x >> 6);  // wave id 0..7
    const int b  = blockIdx.x * WPB + wv;                             // this wave's batch

    unsigned* __restrict__ bpw = bpg + (size_t)b * BP_DWORDS_PER_BATCH;

    __shared__ float ys[WPB][512];           // emitted tags per wave, 16 KB

    // full transitions row for this lane's tag: tr[p] = trans[n][p]
    float tr[64];
    {
        const float4* tr4 = reinterpret_cast<const float4*>(trans + (size_t)n * Sz);
        #pragma unroll
        for (int k = 0; k < 16; ++k) {
            float4 t = tr4[k];
            tr[4 * k + 0] = t.x; tr[4 * k + 1] = t.y;
            tr[4 * k + 2] = t.z; tr[4 * k + 3] = t.w;
        }
    }

    float fv = (n == 0) ? 0.0f : NEGINF;

    const float* lgbase = logits + (size_t)b * Tz * Sz;
    const float* mkbase = masks + (size_t)b * Tz;

    // group-of-4 software-pipelined prefetch (2 groups deep)
    float lgc[4], lgn[4], mkc[4], mkn[4];
    #pragma unroll
    for (int k = 0; k < 4; ++k) {
        lgc[k] = lgbase[(1 + k) * Sz + n];
        mkc[k] = mkbase[1 + k];
        lgn[k] = lgbase[(5 + k) * Sz + n];
        mkn[k] = mkbase[5 + k];
    }

    unsigned pk = 0;

    // ---- one Viterbi step (R10's validated body; literal lanes) ----
    auto step = [&](int k, float lg, float mk) -> float {
        float m[8]; int id[8];
        #pragma unroll
        for (int c = 0; c < 8; ++c) {
            m[c]  = rlf(fv, 8 * c) + tr[8 * c];
            id[c] = 8 * c;
            #pragma unroll
            for (int j = 1; j < 8; ++j) {
                const int p = 8 * c + j;
                float cand = rlf(fv, p) + tr[p];
                bool g = cand > m[c];          // uses OLD m[c]
                id[c] = g ? p : id[c];
                m[c]  = fmaxf(m[c], cand);
            }
        }
        #pragma unroll
        for (int st = 1; st < 8; st <<= 1) {
            #pragma unroll
            for (int c = 0; c < 8; c += 2 * st) {
                bool g = m[c + st] > m[c];
                id[c] = g ? id[c + st] : id[c];
                m[c]  = fmaxf(m[c], m[c + st]);
            }
        }
        pk |= ((unsigned)id[0]) << (8 * k);
        float mm = m[0];
        fv = mm + lg * mk;                     // mask multiplies emission only
        return mm;                             // pre-feat max (for path_score)
    };

    // main: groups g = 0..126 cover steps i = 4g+k (i <= 507)
    for (int g = 0; g < 127; ++g) {
        step(0, lgc[0], mkc[0]);
        step(1, lgc[1], mkc[1]);
        step(2, lgc[2], mkc[2]);
        step(3, lgc[3], mkc[3]);

        bpw[g * 64 + n] = pk;                  // coalesced 256B, fire-and-forget
        pk = 0;

        // rotate prefetch; issue loads for group g+2 (rows 4g+9 .. 4g+12)
        #pragma unroll
        for (int k = 0; k < 4; ++k) { lgc[k] = lgn[k]; mkc[k] = mkn[k]; }
        #pragma unroll
        for (int k = 0; k < 4; ++k) {
            int t = 4 * g + 9 + k;
            t = (t < Tz) ? t : (Tz - 1);
            lgn[k] = lgbase[t * Sz + n];
            mkn[k] = mkbase[t];
        }
    }

    // tail: steps 508, 509, 510 (group 127, k = 0..2)
    step(0, lgc[0], mkc[0]);
    step(1, lgc[1], mkc[1]);
    float psc = step(2, lgc[2], mkc[2]);
    bpw[127 * 64 + n] = pk;                    // flush steps 508..510
    if (n == 63) out[b] = psc;                 // path_score = vmaxs[-1][:,63]

    // make our own bp stores visible to our own loads
    asm volatile("s_waitcnt vmcnt(0)" ::: "memory");

    // ---- backtrace (intra-wave; R10's validated readlane chain, bp from global) ----
    unsigned wcur = bpw[127 * 64 + n];
    int w127_63 = __builtin_amdgcn_readlane((int)wcur, 63);
    int tag = (w127_63 >> 16) & 255;           // t0 = bptrs[510][63]

    for (int g = 127; g >= 0; --g) {
        unsigned wnext = (g > 0) ? bpw[(g - 1) * 64 + n] : 0u;  // prefetch (L2)
        const int smax = (g == 127) ? 2 : 3;
        for (int s = smax; s >= 0; --s) {
            int idx = 4 * g + s;
            if (n == 0) ys[wv][idx] = (float)tag;  // emit BEFORE following ptr
            int wd = __builtin_amdgcn_readlane((int)wcur, tag);  // tag is uniform
            tag = (wd >> (8 * s)) & 255;
        }
        wcur = wnext;
    }

    // same-wave LDS ordering: lane-0 writes above complete before these reads
    float* outseq = out + Bz + (size_t)b * (Tz - 1);
    for (int k = n; k < Tz - 1; k += 64) outseq[k] = ys[wv][k];
}

// ---------------- fallback: R10 kernel (validated, 356 us) ----------------
__global__ __launch_bounds__(64)
void crf_viterbi_kernel(const float* __restrict__ logits,
                        const float* __restrict__ masks,
                        const float* __restrict__ trans,
                        float* __restrict__ out)
{
    const int n = threadIdx.x;
    const int b = blockIdx.x;

    __shared__ unsigned bp[128 * 64];
    __shared__ float ys[Tz - 1];

    float tr[64];
    {
        const float4* tr4 = reinterpret_cast<const float4*>(trans + (size_t)n * Sz);
        #pragma unroll
        for (int k = 0; k < 16; ++k) {
            float4 t = tr4[k];
            tr[4 * k + 0] = t.x; tr[4 * k + 1] = t.y;
            tr[4 * k + 2] = t.z; tr[4 * k + 3] = t.w;
        }
    }

    float fv = (n == 0) ? 0.0f : NEGINF;

    const float* lgbase = logits + (size_t)b * Tz * Sz;
    const float* mkbase = masks + (size_t)b * Tz;

    float lgc[4], lgn[4], mkc[4], mkn[4];
    #pragma unroll
    for (int k = 0; k < 4; ++k) {
        lgc[k] = lgbase[(1 + k) * Sz + n];
        mkc[k] = mkbase[1 + k];
        lgn[k] = lgbase[(5 + k) * Sz + n];
        mkn[k] = mkbase[5 + k];
    }

    unsigned pk = 0;

    auto step = [&](int k, float lg, float mk) -> float {
        float m[8]; int id[8];
        #pragma unroll
        for (int c = 0; c < 8; ++c) {
            m[c]  = rlf(fv, 8 * c) + tr[8 * c];
            id[c] = 8 * c;
            #pragma unroll
            for (int j = 1; j < 8; ++j) {
                const int p = 8 * c + j;
                float cand = rlf(fv, p) + tr[p];
                bool g = cand > m[c];
                id[c] = g ? p : id[c];
                m[c]  = fmaxf(m[c], cand);
            }
        }
        #pragma unroll
        for (int st = 1; st < 8; st <<= 1) {
            #pragma unroll
            for (int c = 0; c < 8; c += 2 * st) {
                bool g = m[c + st] > m[c];
                id[c] = g ? id[c + st] : id[c];
                m[c]  = fmaxf(m[c], m[c + st]);
            }
        }
        pk |= ((unsigned)id[0]) << (8 * k);
        float mm = m[0];
        fv = mm + lg * mk;
        return mm;
    };

    for (int g = 0; g < 127; ++g) {
        step(0, lgc[0], mkc[0]);
        step(1, lgc[1], mkc[1]);
        step(2, lgc[2], mkc[2]);
        step(3, lgc[3], mkc[3]);

        bp[g * 64 + n] = pk;
        pk = 0;

        #pragma unroll
        for (int k = 0; k < 4; ++k) { lgc[k] = lgn[k]; mkc[k] = mkn[k]; }
        #pragma unroll
        for (int k = 0; k < 4; ++k) {
            int t = 4 * g + 9 + k;
            t = (t < Tz) ? t : (Tz - 1);
            lgn[k] = lgbase[t * Sz + n];
            mkn[k] = mkbase[t];
        }
    }

    step(0, lgc[0], mkc[0]);
    step(1, lgc[1], mkc[1]);
    float psc = step(2, lgc[2], mkc[2]);
    bp[127 * 64 + n] = pk;
    if (n == 63) out[b] = psc;

    unsigned wcur = bp[127 * 64 + n];
    int w127_63 = __builtin_amdgcn_readlane((int)wcur, 63);
    int tag = (w127_63 >> 16) & 255;

    for (int g = 127; g >= 0; --g) {
        unsigned wnext = (g > 0) ? bp[(g - 1) * 64 + n] : 0u;
        const int smax = (g == 127) ? 2 : 3;
        for (int s = smax; s >= 0; --s) {
            int idx = 4 * g + s;
            if (n == 0) ys[idx] = (float)tag;
            int wd = __builtin_amdgcn_readlane((int)wcur, tag);
            tag = (wd >> (8 * s)) & 255;
        }
        wcur = wnext;
    }

    __syncthreads();
    float* outseq = out + Bz + (size_t)b * (Tz - 1);
    for (int k = n; k < Tz - 1; k += 64) outseq[k] = ys[k];
}

extern "C" void kernel_launch(void* const* d_in, const int* in_sizes, int n_in,
                              void* d_out, int out_size, void* d_ws, size_t ws_size,
                              hipStream_t stream) {
    const float* logits = (const float*)d_in[0];
    const float* masks  = (const float*)d_in[1];
    const float* trans  = (const float*)d_in[2];
    float* out = (float*)d_out;
    (void)in_sizes; (void)n_in; (void)out_size;

    if (d_ws != nullptr && ws_size >= WS_NEEDED) {
        crf_viterbi_wide<<<dim3(Bz / WPB), dim3(WPB * 64), 0, stream>>>(
            logits, masks, trans, out, (unsigned*)d_ws);
    } else {
        crf_viterbi_kernel<<<dim3(Bz), dim3(64), 0, stream>>>(logits, masks, trans, out);
    }
}